// Round 8
// baseline (103.655 us; speedup 1.0000x reference)
//
#include <hip/hip_runtime.h>

// B=32, C=8, L=2048, K=512, S=64, W=1985
// out[b,0,q] = max(0, max_w sum_c dot(xw_n[b,c,w,:], sn_n[c,q,:]) / 8)

#define B_ 32
#define C_ 8
#define L_ 2048
#define K_ 512
#define S_ 64
#define W_ 1985
#define TW 128                        // windows per block tile

typedef _Float16 f16x8 __attribute__((ext_vector_type(8)));
typedef float f32x16 __attribute__((ext_vector_type(16)));
typedef float f32x4u __attribute__((ext_vector_type(4), aligned(4)));

// ---- prologue: pack shapelets (blocks 0..127) in 32x32x16 B-frag layout,
//      window inv-norms (blocks 128..383) + zero out ----
// Bp unit ((c*4+kq)*16 + nt)*64 + lane:
//   value[j] = sn_norm[c][nt*32 + (lane&31)][kq*16 + (lane>>5)*8 + j]
__global__ __launch_bounds__(256)
void prep_k(const float* __restrict__ x, const float* __restrict__ sh,
            _Float16* __restrict__ Bp, float* __restrict__ invn,
            float* __restrict__ out) {
    __shared__ float xr[L_];             // norm blocks only
    const int tid = threadIdx.x;
    const int blk = blockIdx.x;

    if (blk < 128) {
        const int sb   = blk * 4 + (tid >> 6);   // 0..511 = c(8) x kq(4) x nt(16)
        const int c    = sb >> 6;
        const int kq   = (sb >> 4) & 3;
        const int nt   = sb & 15;
        const int lane = tid & 63;
        const int half = lane >> 5;
        const int q    = nt * 32 + (lane & 31);

        const float4* sp = (const float4*)(sh + (size_t)(c * K_ + q) * S_);
        float ss = 0.f;
        #pragma unroll
        for (int i = 0; i < 8; ++i) {
            float4 v = sp[half * 8 + i];
            ss += v.x * v.x + v.y * v.y + v.z * v.z + v.w * v.w;
        }
        ss += __shfl_xor(ss, 32);
        float inv = 1.f / fmaxf(sqrtf(ss), 1e-8f);

        float4 u0 = sp[kq * 4 + half * 2];
        float4 u1 = sp[kq * 4 + half * 2 + 1];
        f16x8 o;
        o[0] = (_Float16)(u0.x * inv); o[1] = (_Float16)(u0.y * inv);
        o[2] = (_Float16)(u0.z * inv); o[3] = (_Float16)(u0.w * inv);
        o[4] = (_Float16)(u1.x * inv); o[5] = (_Float16)(u1.y * inv);
        o[6] = (_Float16)(u1.z * inv); o[7] = (_Float16)(u1.w * inv);
        ((f16x8*)Bp)[((c * 4 + kq) * 16 + nt) * 64 + lane] = o;
    } else {
        // window inverse norms for row r = b*8+c via sliding sum
        const int r = blk - 128;             // 0..255
        const float* xp = x + (size_t)r * L_;
        for (int i = tid; i < L_ / 4; i += 256)
            ((float4*)xr)[i] = ((const float4*)xp)[i];
        __syncthreads();

        float* ivp = invn + (size_t)r * L_;
        const int w0 = tid * 8;
        float ss = 0.f;
        if (w0 < W_) {
            #pragma unroll
            for (int j = 0; j < S_; ++j) { float v = xr[w0 + j]; ss += v * v; }
        }
        #pragma unroll
        for (int u = 0; u < 8; ++u) {
            int w = w0 + u;
            float o = 0.f;
            if (u > 0 && w < W_)
                ss += xr[w + 63] * xr[w + 63] - xr[w - 1] * xr[w - 1];
            if (w < W_) o = 0.125f / fmaxf(sqrtf(ss), 1e-8f);
            if (w < L_) ivp[w] = o;
        }
        if (r < 64) out[r * 256 + tid] = 0.f;   // zero output
    }
}

// ---- main: barrier-free, software-pipelined MFMA GEMM + relu + max ----
// grid (16 wt, 2 ng, 32 b) = 1024 blocks, 256 threads = 4 independent waves.
// Wave (mg,nw): 64 windows (mt=2 x 32) x 128 cols (nt=4 x 32).
// 32 flat steps s = (c,ks); B loads 2 steps ahead (3-slot ring), A raw loads
// 1 step ahead (2-slot), invn 1 channel ahead. No LDS, no __syncthreads.
__global__ __launch_bounds__(256, 2)
void mcs_k(const float* __restrict__ x, const _Float16* __restrict__ Bp,
           const float* __restrict__ invn, float* __restrict__ out) {
    const int wt  = blockIdx.x;
    const int ng  = blockIdx.y;
    const int b   = blockIdx.z;
    const int tid = threadIdx.x;
    const int lane = tid & 63;
    const int wv   = tid >> 6;
    const int mg   = wv >> 1;
    const int nw   = wv & 1;

    const int l31 = lane & 31;
    const int lh  = lane >> 5;
    const int Wb  = wt * TW + mg * 64;

    const float* xbase  = x    + (size_t)(b * C_) * L_;
    const float* ivbase = invn + (size_t)(b * C_) * L_;
    const f16x8* Bq     = (const f16x8*)Bp;
    const int coloff    = (ng * 8 + nw * 4) * 64 + lane;

    f16x8  Bbuf[3][4];        // 48 VGPRs: B frags, 2-step prefetch ring
    f32x4u Abuf[2][4];        // 32 VGPRs: raw A (x) data, 1-step prefetch
    float  iv0b[2], iv1b[2];  // per-channel row scales, 1-channel prefetch

    auto issueB = [&](int s, int slot) {
        const int c = s >> 2, ks = s & 3;
        const f16x8* bb = Bq + ((c * 4 + ks) * 16) * 64 + coloff;
        #pragma unroll
        for (int nt = 0; nt < 4; ++nt) Bbuf[slot][nt] = bb[nt * 64];
    };
    auto issueA = [&](int s, int slot) {
        const int c = s >> 2, ks = s & 3;
        const float* xr = xbase + c * L_;
        #pragma unroll
        for (int mt = 0; mt < 2; ++mt) {
            int p  = Wb + mt * 32 + l31 + ks * 16 + lh * 8;
            int pc = p <= L_ - 8 ? p : L_ - 8;   // only invalid windows clamp
            Abuf[slot][mt * 2]     = *(const f32x4u*)(xr + pc);
            Abuf[slot][mt * 2 + 1] = *(const f32x4u*)(xr + pc + 4);
        }
    };

    // prolog
    iv0b[0] = ivbase[Wb + l31];           // 0 for invalid windows
    iv1b[0] = ivbase[Wb + 32 + l31];
    issueB(0, 0);
    issueA(0, 0);
    issueB(1, 1);

    f32x16 acc[2][4];
    #pragma unroll
    for (int mt = 0; mt < 2; ++mt)
        #pragma unroll
        for (int nt = 0; nt < 4; ++nt)
            #pragma unroll
            for (int r = 0; r < 16; ++r) acc[mt][nt][r] = 0.f;

    #pragma unroll
    for (int s = 0; s < 32; ++s) {
        const int c = s >> 2, ks = s & 3;
        // issue future loads first
        if (s + 2 < 32) issueB(s + 2, (s + 2) % 3);
        if (s + 1 < 32) issueA(s + 1, (s + 1) & 1);
        if (ks == 0 && c + 1 < C_) {
            const float* ivr = ivbase + (c + 1) * L_;
            iv0b[(c + 1) & 1] = ivr[Wb + l31];
            iv1b[(c + 1) & 1] = ivr[Wb + 32 + l31];
        }
        // build A f16 fragments from raw slot (waits on A loads of step s)
        const float iv0 = iv0b[c & 1], iv1 = iv1b[c & 1];
        f16x8 af0, af1;
        {
            f32x4u v0 = Abuf[s & 1][0], v1 = Abuf[s & 1][1];
            af0[0] = (_Float16)(v0[0] * iv0); af0[1] = (_Float16)(v0[1] * iv0);
            af0[2] = (_Float16)(v0[2] * iv0); af0[3] = (_Float16)(v0[3] * iv0);
            af0[4] = (_Float16)(v1[0] * iv0); af0[5] = (_Float16)(v1[1] * iv0);
            af0[6] = (_Float16)(v1[2] * iv0); af0[7] = (_Float16)(v1[3] * iv0);
            f32x4u w0 = Abuf[s & 1][2], w1 = Abuf[s & 1][3];
            af1[0] = (_Float16)(w0[0] * iv1); af1[1] = (_Float16)(w0[1] * iv1);
            af1[2] = (_Float16)(w0[2] * iv1); af1[3] = (_Float16)(w0[3] * iv1);
            af1[4] = (_Float16)(w1[0] * iv1); af1[5] = (_Float16)(w1[1] * iv1);
            af1[6] = (_Float16)(w1[2] * iv1); af1[7] = (_Float16)(w1[3] * iv1);
        }
        // 8 MFMAs (waits on B loads of step s)
        #pragma unroll
        for (int nt = 0; nt < 4; ++nt) {
            acc[0][nt] = __builtin_amdgcn_mfma_f32_32x32x16_f16(
                af0, Bbuf[s % 3][nt], acc[0][nt], 0, 0, 0);
            acc[1][nt] = __builtin_amdgcn_mfma_f32_32x32x16_f16(
                af1, Bbuf[s % 3][nt], acc[1][nt], 0, 0, 0);
        }
    }

    // epilogue: relu + max over windows (invalid windows exactly 0).
    // 32x32 C/D: col = lane&31; lane and lane^32 cover the same col.
    #pragma unroll
    for (int nt = 0; nt < 4; ++nt) {
        float m = 0.f;
        #pragma unroll
        for (int mt = 0; mt < 2; ++mt)
            #pragma unroll
            for (int r = 0; r < 16; ++r)
                m = fmaxf(m, acc[mt][nt][r]);
        m = fmaxf(m, __shfl_xor(m, 32));
        if (lane < 32)
            atomicMax((unsigned int*)(out + b * K_ + ng * 256 + nw * 128 + nt * 32 + l31),
                      __float_as_uint(m));
    }
}

extern "C" void kernel_launch(void* const* d_in, const int* in_sizes, int n_in,
                              void* d_out, int out_size, void* d_ws, size_t ws_size,
                              hipStream_t stream) {
    const float* x  = (const float*)d_in[0];   // (32, 8, 2048) fp32
    const float* sh = (const float*)d_in[1];   // (8, 512, 64) fp32
    float* out = (float*)d_out;                // (32, 1, 512) fp32
    _Float16* Bp  = (_Float16*)d_ws;           // 512 KB packed shapelets
    float* invn   = (float*)((char*)d_ws + (size_t)K_ * 512 * sizeof(_Float16)); // 2 MB

    prep_k<<<dim3(384), dim3(256), 0, stream>>>(x, sh, Bp, invn, out);
    mcs_k<<<dim3(16, 2, B_), dim3(256), 0, stream>>>(x, Bp, invn, out);
}